// Round 16
// baseline (675.185 us; speedup 1.0000x reference)
//
#include <hip/hip_runtime.h>
#include <float.h>

#define KC 4096
#define DIM 256
#define MB 16384            // m per batch element (16*32*32)
#define NTOT 65536          // rows
#define ZELEMS 16777216
#define LOSS_OFF 16777216
#define IDX_OFF  16777217
// TAU: 2*(grid ULP(256)=3.05e-5) + 2*fp16-chain score err (<=4.7e-5 worst) + slack.
// Validated empirically at 1.5e-4 in R11-R15 (0 misses across 65536 rows).
#define TAU 1.5e-4f

// scratch inside z_q output region (fully overwritten by vq_apply at the end):
// [0, 524288)       fp16 e' A-fragment table (2MB)
#define BT_OFF   524288     // f32 |e_k|^2 table, 4096 floats
#define CNT_OFF  528400     // 2 uints (cand count, full count)
#define CAND_OFF 532480     // uint4 entries (16B each), cap 65536
#define FULL_OFF 800000     // uint entries, cap 65536

typedef _Float16 h8 __attribute__((ext_vector_type(8)));
typedef float f4v __attribute__((ext_vector_type(4)));

__device__ __forceinline__ bool lexlt(float av, int ai, float bv, int bi) {
    return (av < bv) || (av == bv && ai < bi);
}

// ---- P: fused prep. Blocks 0-511: fp16 e'=e*4096 A-frag table (R10-R15
// verified geometry). Blocks 512-1535: |e|^2 (fp64->f32), one wave per code. ----
__global__ __launch_bounds__(256) void vq_prep(const float* __restrict__ e,
                                               float* __restrict__ out) {
    if (blockIdx.x < 512) {
        int t = blockIdx.x * 256 + threadIdx.x;        // 0..131071
        int code = t >> 5, s8 = t & 31;
        const float4* src = reinterpret_cast<const float4*>(e + (size_t)code * DIM + s8 * 8);
        float4 v0 = src[0], v1 = src[1];
        float f[8] = {v0.x, v0.y, v0.z, v0.w, v1.x, v1.y, v1.z, v1.w};
        union { uint4 q; _Float16 h[8]; } P;
        #pragma unroll
        for (int p = 0; p < 8; ++p) P.h[p] = (_Float16)(f[p] * 4096.0f);
        int kc = s8 >> 2, khi = s8 & 3;
        int lane = khi * 16 + (code & 15);
        int slot = ((code >> 4) * 8 + kc) * 64 + lane;
        reinterpret_cast<uint4*>(out)[slot] = P.q;
    } else {
        int k = (blockIdx.x - 512) * 4 + (threadIdx.x >> 6);   // 0..4095
        int lane = threadIdx.x & 63;
        float4 v = reinterpret_cast<const float4*>(e + (size_t)k * DIM)[lane];
        double s = (double)v.x * v.x + (double)v.y * v.y + (double)v.z * v.z + (double)v.w * v.w;
        #pragma unroll
        for (int off = 32; off > 0; off >>= 1) s += __shfl_down(s, off);
        if (lane == 0) out[BT_OFF + k] = (float)s;
    }
}

// ---- K1: fp16 MFMA, TWO-PASS exact-window, 4 row-sets per wave. ----
// Block = 256 rows (4 waves x 64 rows). Each staged A-frag feeds 4 MFMAs.
// Pass 1: exact top-1. Pass 2: bitwise-identical recompute, collect all
// scores <= b1+TAU. Classes: 1 clean; 2..4 cand; >=5 full.
__global__ __launch_bounds__(256) void vq_fast(const float* __restrict__ z,
                                               float* __restrict__ out) {
    __shared__ uint4 etile[2][512];                // 16KB double-buffered tile
    __shared__ unsigned long long lists[4][64][4]; // (wave,row,khi) packed W-list
    const int tid = threadIdx.x;
    const int wave = tid >> 6, lane = tid & 63;
    const int khi = lane >> 4, l16 = lane & 15;
    const int nbase = blockIdx.x * 256;
    const int b = nbase / MB;
    const int mbase = nbase % MB;
    const float* zb = z + (size_t)b * DIM * MB + mbase + wave * 64 + l16;

    // z B-fragments (fp16), 4 row-sets x 8 kc (128 VGPR)
    h8 zf[4][8];
    #pragma unroll
    for (int kc = 0; kc < 8; ++kc) {
        #pragma unroll
        for (int s = 0; s < 4; ++s) {
            h8 v;
            #pragma unroll
            for (int j = 0; j < 8; ++j)
                v[j] = (_Float16)zb[(size_t)(kc * 32 + khi * 8 + j) * MB + s * 16];
            zf[s][kc] = v;
        }
    }

    const uint4* ET = reinterpret_cast<const uint4*>(out);
    const float* Btab = out + BT_OFF;

    // ---------------- pass 1: top-1 ----------------
    float b1[4] = {FLT_MAX, FLT_MAX, FLT_MAX, FLT_MAX};
    int k1[4] = {0, 0, 0, 0};
    {
        uint4 r0 = ET[tid], r1 = ET[tid + 256];
        for (int tile = 0; tile < KC / 16; ++tile) {
            const int cur = tile & 1;
            etile[cur][tid] = r0; etile[cur][tid + 256] = r1;
            __syncthreads();
            if (tile < KC / 16 - 1) {
                r0 = ET[(size_t)(tile + 1) * 512 + tid];
                r1 = ET[(size_t)(tile + 1) * 512 + tid + 256];
            }
            f4v acc[4];
            #pragma unroll
            for (int s = 0; s < 4; ++s) acc[s] = (f4v){0.f, 0.f, 0.f, 0.f};
            #pragma unroll
            for (int kc = 0; kc < 8; ++kc) {
                union { uint4 q; h8 v; } af;
                af.q = etile[cur][kc * 64 + lane];
                #pragma unroll
                for (int s = 0; s < 4; ++s)
                    acc[s] = __builtin_amdgcn_mfma_f32_16x16x32_f16(af.v, zf[s][kc], acc[s], 0, 0, 0);
            }
            const f4v Bv = *reinterpret_cast<const f4v*>(Btab + tile * 16 + khi * 4);
            const int kb = tile * 16 + khi * 4;
            #pragma unroll
            for (int s = 0; s < 4; ++s) {
                float sc[4];
                #pragma unroll
                for (int i = 0; i < 4; ++i) sc[i] = fmaf(-4.8828125e-4f, acc[s][i], Bv[i]);
                float m = fminf(fminf(sc[0], sc[1]), fminf(sc[2], sc[3]));
                if (m < b1[s]) {                   // rare: detail, strict <, ascending i
                    #pragma unroll
                    for (int i = 0; i < 4; ++i)
                        if (sc[i] < b1[s]) { b1[s] = sc[i]; k1[s] = kb + i; }
                }
            }
            __syncthreads();
        }
    }
    // merge top-1 across the 4 khi groups (lex: value then index)
    #pragma unroll
    for (int off = 16; off < 64; off <<= 1) {
        #pragma unroll
        for (int s = 0; s < 4; ++s) {
            float ov = __shfl_xor(b1[s], off); int ok = __shfl_xor(k1[s], off);
            if (lexlt(ov, ok, b1[s], k1[s])) { b1[s] = ov; k1[s] = ok; }
        }
    }
    float thr[4];
    #pragma unroll
    for (int s = 0; s < 4; ++s) thr[s] = b1[s] + TAU;

    // ---------------- pass 2: exact window collect ----------------
    int cnt[4] = {0, 0, 0, 0};
    int cc[4][4];
    #pragma unroll
    for (int s = 0; s < 4; ++s) { cc[s][0] = cc[s][1] = cc[s][2] = cc[s][3] = 0; }
    {
        uint4 r0 = ET[tid], r1 = ET[tid + 256];
        __syncthreads();                            // pass1's last reads done
        for (int tile = 0; tile < KC / 16; ++tile) {
            const int cur = tile & 1;
            etile[cur][tid] = r0; etile[cur][tid + 256] = r1;
            __syncthreads();
            if (tile < KC / 16 - 1) {
                r0 = ET[(size_t)(tile + 1) * 512 + tid];
                r1 = ET[(size_t)(tile + 1) * 512 + tid + 256];
            }
            f4v acc[4];
            #pragma unroll
            for (int s = 0; s < 4; ++s) acc[s] = (f4v){0.f, 0.f, 0.f, 0.f};
            #pragma unroll
            for (int kc = 0; kc < 8; ++kc) {
                union { uint4 q; h8 v; } af;
                af.q = etile[cur][kc * 64 + lane];
                #pragma unroll
                for (int s = 0; s < 4; ++s)
                    acc[s] = __builtin_amdgcn_mfma_f32_16x16x32_f16(af.v, zf[s][kc], acc[s], 0, 0, 0);
            }
            const f4v Bv = *reinterpret_cast<const f4v*>(Btab + tile * 16 + khi * 4);
            const int kb = tile * 16 + khi * 4;
            #pragma unroll
            for (int s = 0; s < 4; ++s) {
                float sc[4];
                #pragma unroll
                for (int i = 0; i < 4; ++i) sc[i] = fmaf(-4.8828125e-4f, acc[s][i], Bv[i]);
                float m = fminf(fminf(sc[0], sc[1]), fminf(sc[2], sc[3]));
                if (m <= thr[s]) {                 // rare: collect members
                    #pragma unroll
                    for (int i = 0; i < 4; ++i)
                        if (sc[i] <= thr[s]) {
                            int k = kb + i;
                            if (cnt[s] == 0) cc[s][0] = k;
                            else if (cnt[s] == 1) cc[s][1] = k;
                            else if (cnt[s] == 2) cc[s][2] = k;
                            else if (cnt[s] == 3) cc[s][3] = k;
                            cnt[s]++;
                        }
                }
            }
            __syncthreads();
        }
    }
    // pack per-lane lists: 4x12b ks + 8b cnt (saturate 15)
    #pragma unroll
    for (int s = 0; s < 4; ++s) {
        unsigned long long p = (unsigned long long)(cnt[s] > 15 ? 15 : cnt[s]) << 48 |
            (unsigned long long)cc[s][0] | ((unsigned long long)cc[s][1] << 12) |
            ((unsigned long long)cc[s][2] << 24) | ((unsigned long long)cc[s][3] << 36);
        lists[wave][s * 16 + l16][khi] = p;
    }
    __syncthreads();

    // gather + classify + emit (lanes<16 own one row per set)
    unsigned* cntg = (unsigned*)(out + CNT_OFF);
    #pragma unroll
    for (int set = 0; set < 4; ++set) {
        bool act = (lane < 16);
        int gidx = nbase + wave * 64 + set * 16 + l16;
        int I1 = k1[set];
        int tot = 0, c[4];
        c[0] = c[1] = c[2] = c[3] = I1;            // pad with best (harmless dup)
        if (act) {
            #pragma unroll
            for (int q = 0; q < 4; ++q) {
                unsigned long long pl = lists[wave][set * 16 + l16][q];
                int pc = (int)(pl >> 48);
                #pragma unroll
                for (int j = 0; j < 4; ++j) {
                    int kv = (int)((pl >> (12 * j)) & 4095ull);
                    if (j < pc && tot + j < 4) c[tot + j] = kv;
                }
                tot += pc;
            }
            out[IDX_OFF + gidx] = (float)I1;       // final for clean; placeholder else
        }
        bool cand = act && (tot >= 2) && (tot <= 4);
        bool full = act && (tot > 4);
        unsigned long long mc = __ballot(cand);
        if (mc) {
            int leader = __ffsll((long long)mc) - 1;
            unsigned base = 0;
            if (lane == leader) base = atomicAdd(cntg, (unsigned)__popcll(mc));
            base = __shfl(base, leader);
            if (cand) {
                unsigned pos = base + (unsigned)__popcll(mc & ((1ull << lane) - 1ull));
                reinterpret_cast<uint4*>(out + CAND_OFF)[pos] =
                    make_uint4((unsigned)gidx,
                               (unsigned)c[0] | ((unsigned)c[1] << 16),
                               (unsigned)c[2] | ((unsigned)c[3] << 16), 0u);
            }
        }
        unsigned long long mf = __ballot(full);
        if (mf) {
            int leader = __ffsll((long long)mf) - 1;
            unsigned base = 0;
            if (lane == leader) base = atomicAdd(cntg + 1, (unsigned)__popcll(mf));
            base = __shfl(base, leader);
            if (full) {
                unsigned pos = base + (unsigned)__popcll(mf & ((1ull << lane) - 1ull));
                reinterpret_cast<unsigned*>(out + FULL_OFF)[pos] = (unsigned)gidx;
            }
        }
    }
}

// ---- K2a: candidate rescore (<=4 codes), grid-stride waves (R12-proven) ----
__global__ __launch_bounds__(256) void vq_resolve_cand(const float* __restrict__ z,
                                                       const float* __restrict__ e,
                                                       float* __restrict__ out) {
    const int wave = threadIdx.x >> 6, lane = threadIdx.x & 63;
    const unsigned n = *reinterpret_cast<const unsigned*>(out + CNT_OFF);
    const uint4* list = reinterpret_cast<const uint4*>(out + CAND_OFF);
    for (unsigned ei = blockIdx.x * 4 + wave; ei < n; ei += gridDim.x * 4) {
        uint4 ent = list[ei];
        const int gidx = (int)ent.x;
        const int c1 = (int)(ent.y & 0xFFFFu), c2 = (int)(ent.y >> 16);
        const int c3 = (int)(ent.z & 0xFFFFu), c4 = (int)(ent.z >> 16);
        const int b = gidx >> 14, m = gidx & (MB - 1);
        const float* zr = z + (size_t)b * DIM * MB + m;
        const float* e1 = e + (size_t)c1 * DIM;
        const float* e2 = e + (size_t)c2 * DIM;
        const float* e3 = e + (size_t)c3 * DIM;
        const float* e4 = e + (size_t)c4 * DIM;
        double A = 0.0;
        double d1 = 0.0, d2 = 0.0, d3 = 0.0, d4 = 0.0;
        double q1 = 0.0, q2 = 0.0, q3 = 0.0, q4 = 0.0;
        #pragma unroll
        for (int jj = 0; jj < 4; ++jj) {
            int d = lane * 4 + jj;
            double zv = (double)zr[(size_t)d * MB];
            double v1 = (double)e1[d], v2 = (double)e2[d];
            double v3 = (double)e3[d], v4 = (double)e4[d];
            A = fma(zv, zv, A);
            d1 = fma(zv, v1, d1); q1 = fma(v1, v1, q1);
            d2 = fma(zv, v2, d2); q2 = fma(v2, v2, q2);
            d3 = fma(zv, v3, d3); q3 = fma(v3, v3, q3);
            d4 = fma(zv, v4, d4); q4 = fma(v4, v4, q4);
        }
        #pragma unroll
        for (int mm = 1; mm < 64; mm <<= 1) {
            A += __shfl_xor(A, mm);
            d1 += __shfl_xor(d1, mm); q1 += __shfl_xor(q1, mm);
            d2 += __shfl_xor(d2, mm); q2 += __shfl_xor(q2, mm);
            d3 += __shfl_xor(d3, mm); q3 += __shfl_xor(q3, mm);
            d4 += __shfl_xor(d4, mm); q4 += __shfl_xor(q4, mm);
        }
        if (lane == 0) {
            float Af = (float)A;
            float s1 = (Af - (float)(2.0 * d1)) + (float)q1;
            float s2 = (Af - (float)(2.0 * d2)) + (float)q2;
            float s3 = (Af - (float)(2.0 * d3)) + (float)q3;
            float s4 = (Af - (float)(2.0 * d4)) + (float)q4;
            float bv = s1; int bk = c1;
            if (lexlt(s2, c2, bv, bk)) { bv = s2; bk = c2; }
            if (lexlt(s3, c3, bv, bk)) { bv = s3; bk = c3; }
            if (lexlt(s4, c4, bv, bk)) { bv = s4; bk = c4; }
            out[IDX_OFF + gidx] = (float)bk;
        }
    }
}

// ---- K2b: full exact rescan, grid-stride blocks (R12-proven) ----
__global__ __launch_bounds__(256) void vq_resolve_full(const float* __restrict__ z,
                                                       const float* __restrict__ e,
                                                       float* __restrict__ out) {
    __shared__ float zs[DIM];
    __shared__ float rv[4];
    __shared__ int ri[4];
    const int tid = threadIdx.x;
    const int wave = tid >> 6, lane = tid & 63;
    const unsigned n = reinterpret_cast<const unsigned*>(out + CNT_OFF)[1];
    const unsigned* list = reinterpret_cast<const unsigned*>(out + FULL_OFF);
    for (unsigned ei = blockIdx.x; ei < n; ei += gridDim.x) {
        const int gidx = (int)list[ei];
        const int b = gidx >> 14, m = gidx & (MB - 1);
        const float* zr = z + (size_t)b * DIM * MB + m;
        if (tid < DIM) zs[tid] = zr[(size_t)tid * MB];
        __syncthreads();
        double av = 0.0;
        #pragma unroll
        for (int t2 = 0; t2 < 4; ++t2) {
            double zv = (double)zs[lane * 4 + t2];
            av = fma(zv, zv, av);
        }
        #pragma unroll
        for (int mm = 1; mm < 64; mm <<= 1) av += __shfl_xor(av, mm);
        const float Af = (float)av;

        float bsv = FLT_MAX; int bsk = 0;
        for (int kk = 0; kk < 16; ++kk) {
            const int k = kk * 256 + tid;          // ascending per thread
            const float4* er4 = reinterpret_cast<const float4*>(e + (size_t)k * DIM);
            const float4* zs4 = reinterpret_cast<const float4*>(zs);
            double dot0 = 0.0, dot1 = 0.0, q0 = 0.0, q1 = 0.0;
            #pragma unroll 8
            for (int d4 = 0; d4 < 64; ++d4) {
                float4 ev = er4[d4];
                float4 zv = zs4[d4];
                dot0 = fma((double)zv.x, (double)ev.x, dot0);
                dot1 = fma((double)zv.y, (double)ev.y, dot1);
                dot0 = fma((double)zv.z, (double)ev.z, dot0);
                dot1 = fma((double)zv.w, (double)ev.w, dot1);
                q0 = fma((double)ev.x, (double)ev.x, q0);
                q1 = fma((double)ev.y, (double)ev.y, q1);
                q0 = fma((double)ev.z, (double)ev.z, q0);
                q1 = fma((double)ev.w, (double)ev.w, q1);
            }
            float s = (Af - (float)(2.0 * (dot0 + dot1))) + (float)(q0 + q1);
            if (s < bsv) { bsv = s; bsk = k; }
        }
        #pragma unroll
        for (int mm = 1; mm < 64; mm <<= 1) {
            float ov = __shfl_xor(bsv, mm);
            int oi = __shfl_xor(bsk, mm);
            if (ov < bsv || (ov == bsv && oi < bsk)) { bsv = ov; bsk = oi; }
        }
        if (lane == 0) { rv[wave] = bsv; ri[wave] = bsk; }
        __syncthreads();
        if (tid == 0) {
            float bv = rv[0]; int bk = ri[0];
            #pragma unroll
            for (int wv = 1; wv < 4; ++wv) {
                if (rv[wv] < bv || (rv[wv] == bv && ri[wv] < bk)) { bv = rv[wv]; bk = ri[wv]; }
            }
            out[IDX_OFF + gidx] = (float)bk;
        }
        __syncthreads();
    }
}

// ---- K3: z_q scatter + fused loss; e-rows staged in LDS (R12-proven) ----
__global__ __launch_bounds__(256) void vq_apply(const float* __restrict__ z,
                                                const float* __restrict__ e,
                                                float* __restrict__ out) {
    __shared__ int lds_fi[64];
    __shared__ float lds_e[64][260];
    __shared__ double lds_ls[4];
    const int tid = threadIdx.x;
    const int wave = tid >> 6, lane = tid & 63;
    const int nbase = blockIdx.x * 64;
    const int b = nbase / MB;
    const int mbase = nbase % MB;
    if (tid < 64) lds_fi[tid] = (int)out[IDX_OFF + nbase + tid];
    __syncthreads();
    for (int r = wave; r < 64; r += 4) {
        int code = lds_fi[r];
        float4 v = reinterpret_cast<const float4*>(e + (size_t)code * DIM)[lane];
        *reinterpret_cast<float4*>(&lds_e[r][lane * 4]) = v;
    }
    __syncthreads();

    double lsum = 0.0;
    const int mloc = tid & 63;
    const int d0 = tid >> 6;
    #pragma unroll 4
    for (int d = d0; d < DIM; d += 4) {
        float ev = lds_e[mloc][d];
        size_t off = (size_t)b * (DIM * MB) + (size_t)d * MB + mbase + mloc;
        float zv = z[off];
        out[off] = ev;
        float diff = ev - zv;
        lsum += (double)diff * diff;
    }
    #pragma unroll
    for (int off = 32; off > 0; off >>= 1) lsum += __shfl_down(lsum, off);
    if (lane == 0) lds_ls[wave] = lsum;
    __syncthreads();
    if (tid == 0) {
        double t = lds_ls[0] + lds_ls[1] + lds_ls[2] + lds_ls[3];
        atomicAdd(out + LOSS_OFF, (float)(t * (1.25 / (double)ZELEMS)));
    }
}

extern "C" void kernel_launch(void* const* d_in, const int* in_sizes, int n_in,
                              void* d_out, int out_size, void* d_ws, size_t ws_size,
                              hipStream_t stream) {
    const float* z = (const float*)d_in[0];    // [4,256,16,32,32] fp32
    const float* e = (const float*)d_in[1];    // [4096,256] fp32
    float* out = (float*)d_out;

    hipMemsetAsync(out + LOSS_OFF, 0, sizeof(float), stream);
    hipMemsetAsync(out + CNT_OFF, 0, 2 * sizeof(unsigned), stream);
    vq_prep<<<1536, 256, 0, stream>>>(e, out);
    vq_fast<<<NTOT / 256, 256, 0, stream>>>(z, out);
    vq_resolve_cand<<<256, 256, 0, stream>>>(z, e, out);
    vq_resolve_full<<<512, 256, 0, stream>>>(z, e, out);
    vq_apply<<<NTOT / 64, 256, 0, stream>>>(z, e, out);
}